// Round 1
// 563.700 us; speedup vs baseline: 1.2270x; 1.2270x over previous
//
#include <hip/hip_runtime.h>
#include <math.h>

typedef unsigned short u16;
typedef __attribute__((ext_vector_type(8))) __bf16 bf16x8;
typedef __attribute__((ext_vector_type(8))) u16 u16x8;
typedef __attribute__((ext_vector_type(4))) float f32x4;

// ---------- bf16 helpers ----------
__device__ __forceinline__ float b2f(u16 u) {
    union { unsigned int u; float f; } a; a.u = ((unsigned int)u) << 16; return a.f;
}
// HW pack (v_cvt_pk_bf16_f32, RNE) — compiler emits it for the scalar cast (m240)
__device__ __forceinline__ u16 f2b(float f) {
    union { __bf16 h; u16 u; } c; c.h = (__bf16)f; return c.u;
}

// tanh-form GELU in sigmoid form: x*sigmoid(1.5958*(x+0.044715x^3)) = x*e/(e+1).
// rcp instead of full fp32 divide (~9 VALU ops vs ~21; bf16-output accuracy ample).
__device__ __forceinline__ float gelu_t(float x) {
    float x2 = x * x;
    float u  = x * fmaf(0.0713548162726f, x2, 1.5957691216057308f);
    float e  = __expf(u);
    return x * e * __builtin_amdgcn_rcpf(e + 1.0f);
}

// window row -> spatial row (B=32, H=W=56, ws=7, 8x8 windows per image)
__device__ __forceinline__ int win2spatial(int r) {
    int wid = r / 49;
    int n   = r - wid * 49;
    int b   = wid >> 6;
    int wr  = wid & 63;
    int h   = (wr >> 3) * 7 + n / 7;
    int w   = (wr & 7) * 7 + n % 7;
    return (b * 56 + h) * 56 + w;
}

// async global->LDS, 16B per lane. lds dest must be wave-uniform (HW adds lane*16).
__device__ __forceinline__ void stage16(const u16* g, u16* l) {
    __builtin_amdgcn_global_load_lds((const __attribute__((address_space(1))) void*)g,
                                     (__attribute__((address_space(3))) void*)l, 16, 0, 0);
}

// ---------- fp32 -> bf16 conversion (weights) ----------
__global__ __launch_bounds__(256) void cvt_kernel(const float* __restrict__ in,
                                                  u16* __restrict__ out, int n)
{
    int i = (blockIdx.x * 256 + threadIdx.x) * 4;
    if (i < n) {
        float4 v = *reinterpret_cast<const float4*>(in + i);
        ushort4 o;
        o.x = f2b(v.x); o.y = f2b(v.y); o.z = f2b(v.z); o.w = f2b(v.w);
        *reinterpret_cast<ushort4*>(out + i) = o;
    }
}

// ---------- bias tile prep: btile[head][64][64] fp32, -1e30 outside 49x49 ----------
__global__ __launch_bounds__(256) void bias_prep(const float* __restrict__ btab,
                                                 float* __restrict__ btile)
{
    int head = blockIdx.x;
    for (int idx = threadIdx.x; idx < 4096; idx += 256) {
        int i = idx >> 6, j = idx & 63;
        float v = -1e30f;
        if (i < 49 && j < 49) {
            int di = i / 7 - j / 7 + 6;
            int dj = i % 7 - j % 7 + 6;
            v = btab[(di * 13 + dj) * 8 + head];
        }
        btile[head * 4096 + idx] = v;
    }
}

// ---------- LayerNorm: read fp32/bf16 rows, write bf16 rows ----------
template<int REORDER, int INBF>
__global__ __launch_bounds__(256) void ln_kernel(const void* __restrict__ inp,
                                                 const float* __restrict__ gw,
                                                 const float* __restrict__ bw,
                                                 u16* __restrict__ outp)
{
    int wave = threadIdx.x >> 6, lane = threadIdx.x & 63;
    int row  = blockIdx.x * 4 + wave;
    int irow = REORDER ? win2spatial(row) : row;

    float v[4];
    if (INBF) {
        ushort4 xx = *reinterpret_cast<const ushort4*>((const u16*)inp + (size_t)irow * 256 + lane * 4);
        v[0] = b2f(xx.x); v[1] = b2f(xx.y); v[2] = b2f(xx.z); v[3] = b2f(xx.w);
    } else {
        float4 xx = *reinterpret_cast<const float4*>((const float*)inp + (size_t)irow * 256 + lane * 4);
        v[0] = xx.x; v[1] = xx.y; v[2] = xx.z; v[3] = xx.w;
    }

    float s = v[0] + v[1] + v[2] + v[3];
    float q = v[0]*v[0] + v[1]*v[1] + v[2]*v[2] + v[3]*v[3];
#pragma unroll
    for (int off = 32; off > 0; off >>= 1) {
        s += __shfl_xor(s, off, 64);
        q += __shfl_xor(q, off, 64);
    }
    float mean = s * (1.0f / 256.0f);
    float var  = q * (1.0f / 256.0f) - mean * mean;
    float rstd = rsqrtf(var + 1e-5f);

    int c = lane * 4;
    ushort4 o;
    o.x = f2b((v[0] - mean) * rstd * gw[c + 0] + bw[c + 0]);
    o.y = f2b((v[1] - mean) * rstd * gw[c + 1] + bw[c + 1]);
    o.z = f2b((v[2] - mean) * rstd * gw[c + 2] + bw[c + 2]);
    o.w = f2b((v[3] - mean) * rstd * gw[c + 3] + bw[c + 3]);
    *reinterpret_cast<ushort4*>(outp + (size_t)row * 256 + c) = o;
}

// ---------- GEMM: C[M,N] = A[M,K](bf16) @ W[N,K](bf16)^T + bias(f32) ----------
// 128x128 tile, BK=64, 4 waves x 64x64.
// A double-buffered (streamed from HBM, prefetched 1 K-step ahead with counted
// vmcnt across raw s_barriers — T3/T4 minimum 2-phase); B single-buffered
// (weights, L2-hot). LDS 48KB -> 3 blocks/CU.
// EPI 0: bf16 C via LDS-transpose -> dwordx4 stores
// EPI 1: tanh-GELU, bf16 C via transpose
// EPI 2: x1[win2spatial(row)] = bf16(residF[spatial] + val), via transpose
// EPI 3: outF[row] = b2f(residU[row]) + b2f(val)  — via transpose, u16x8 resid
//        reads + float4 stores (full write granules)
template<int EPI>
__global__ __launch_bounds__(256) void gemm_kernel(
    const u16* __restrict__ A, const u16* __restrict__ W,
    const float* __restrict__ bias,
    u16* __restrict__ outU, float* __restrict__ outF,
    const float* __restrict__ residF, const u16* __restrict__ residU,
    int N, int K, int nB)
{
    __shared__ char smem[49152];
    u16* sA0 = (u16*)smem;             // A buf 0, 16 KB
    u16* sA1 = (u16*)(smem + 16384);   // A buf 1, 16 KB
    u16* sB  = (u16*)(smem + 32768);   // B, 16 KB

    int t = threadIdx.x;
    int w = t >> 6, lane = t & 63;
    int quad = lane >> 4, l16 = lane & 15;
    int wm = (w >> 1) * 64, wn = (w & 1) * 64;

    // XCD-aware swizzle: b%8 = XCD; within an XCD, iterate n fastest.
    int b = blockIdx.x;
    int xcd = b & 7, g = b >> 3;
    int n_i = g % nB;
    int m_i = (g / nB) * 8 + xcd;
    int n_blk = n_i * 128, m_blk = m_i * 128;

    int srow = t >> 3;
    int scol = ((t & 7) ^ (srow & 7)) * 8;
    const u16* pA = A + (size_t)(m_blk + srow) * K + scol;
    const u16* pB = W + (size_t)(n_blk + srow) * K + scol;
    u16* lA0 = sA0 + w * 512;
    u16* lA1 = sA1 + w * 512;
    u16* lB  = sB  + w * 512;

    f32x4 acc[4][4];
#pragma unroll
    for (int i = 0; i < 4; ++i)
#pragma unroll
        for (int j = 0; j < 4; ++j) acc[i][j] = (f32x4){0.f, 0.f, 0.f, 0.f};

    int nk = K >> 6;

    // prologue: prefetch A tile 0
#pragma unroll
    for (int gg = 0; gg < 4; ++gg)
        stage16(pA + (size_t)(gg * 32) * K, lA0 + gg * 2048);

    for (int tt = 0; tt < nk; ++tt) {
        int kb = tt << 6;
        // all waves done reading sB / the A buffer we are about to overwrite
        __builtin_amdgcn_s_barrier();
        // issue order matters: B first, then A-next, so the counted "newest 4"
        // at vmcnt(4) are exactly the A-prefetch.
#pragma unroll
        for (int gg = 0; gg < 4; ++gg)
            stage16(pB + (size_t)(gg * 32) * K + kb, lB + gg * 2048);
        if (tt + 1 < nk) {
            u16* lAn = (tt & 1) ? lA0 : lA1;
#pragma unroll
            for (int gg = 0; gg < 4; ++gg)
                stage16(pA + (size_t)(gg * 32) * K + kb + 64, lAn + gg * 2048);
            asm volatile("s_waitcnt vmcnt(4)" ::: "memory");  // A(tt)+B(tt) landed
        } else {
            asm volatile("s_waitcnt vmcnt(0)" ::: "memory");  // drain on last tile
        }
        __builtin_amdgcn_s_barrier();

        const u16* cA = (tt & 1) ? sA1 : sA0;
#pragma unroll
        for (int q32 = 0; q32 < 2; ++q32) {
            bf16x8 af[4], bfr[4];
            int kc = q32 * 4 + quad;
#pragma unroll
            for (int tm = 0; tm < 4; ++tm) {
                int row = wm + tm * 16 + l16;
                af[tm] = *(const bf16x8*)(cA + (unsigned)(row * 8 + (kc ^ (row & 7))) * 8);
            }
#pragma unroll
            for (int tn = 0; tn < 4; ++tn) {
                int row = wn + tn * 16 + l16;
                bfr[tn] = *(const bf16x8*)(sB + (unsigned)(row * 8 + (kc ^ (row & 7))) * 8);
            }
#pragma unroll
            for (int tm = 0; tm < 4; ++tm)
#pragma unroll
                for (int tn = 0; tn < 4; ++tn)
                    acc[tm][tn] = __builtin_amdgcn_mfma_f32_16x16x32_bf16(af[tm], bfr[tn], acc[tm][tn], 0, 0, 0);
        }
    }

    // ---- epilogue: transpose via wave-private LDS, stride 72 u16 (36 dwords:
    // quad rows differ by 4 -> 4*36 mod 32 = 16 -> 2-way write alias = free;
    // row*144 B keeps u16x8 reads 16B-aligned) ----
    __syncthreads();   // all waves done with sA/sB
    u16* tp = (u16*)smem + w * 4608;   // 9216 B per wave (36864 total)

#pragma unroll
    for (int tm = 0; tm < 4; ++tm)
#pragma unroll
        for (int r = 0; r < 4; ++r) {
            int rowL = tm * 16 + quad * 4 + r;
            int srw = 0;
            if (EPI == 2) srw = win2spatial(m_blk + wm + rowL);  // 16x, not 64x
#pragma unroll
            for (int tn = 0; tn < 4; ++tn) {
                int colL = tn * 16 + l16;
                float val = acc[tm][tn][r] + bias[n_blk + wn + colL];
                if (EPI == 1) val = gelu_t(val);
                if (EPI == 2) val += residF[(size_t)srw * 256 + n_blk + wn + colL];
                tp[rowL * 72 + colL] = f2b(val);
            }
        }

    // wave-private region: compiler inserts lgkmcnt wait on the dependency
#pragma unroll
    for (int it = 0; it < 8; ++it) {
        int rowL = it * 8 + (lane >> 3);
        int chunk = (lane & 7) * 8;
        u16x8 vv = *(const u16x8*)(tp + rowL * 72 + chunk);
        int grow = m_blk + wm + rowL;
        if (EPI == 3) {
            size_t o = (size_t)grow * N + n_blk + wn + chunk;
            u16x8 rr = *(const u16x8*)(residU + o);
            float4 f0, f1;
            f0.x = b2f(vv[0]) + b2f(rr[0]);
            f0.y = b2f(vv[1]) + b2f(rr[1]);
            f0.z = b2f(vv[2]) + b2f(rr[2]);
            f0.w = b2f(vv[3]) + b2f(rr[3]);
            f1.x = b2f(vv[4]) + b2f(rr[4]);
            f1.y = b2f(vv[5]) + b2f(rr[5]);
            f1.z = b2f(vv[6]) + b2f(rr[6]);
            f1.w = b2f(vv[7]) + b2f(rr[7]);
            *reinterpret_cast<float4*>(outF + o)     = f0;
            *reinterpret_cast<float4*>(outF + o + 4) = f1;
        } else if (EPI == 2) {
            *(u16x8*)(outU + (size_t)win2spatial(grow) * 256 + n_blk + wn + chunk) = vv;
        } else {
            *(u16x8*)(outU + (size_t)grow * N + n_blk + wn + chunk) = vv;
        }
    }
}

// ---------- MFMA window attention ----------
__global__ __launch_bounds__(64) void attn_kernel(const u16* __restrict__ qkv,
                                                  const float* __restrict__ btile,
                                                  u16* __restrict__ o)
{
    __shared__ u16 vT[32 * 72];
    __shared__ u16 pl[64 * 72];

    int wid = blockIdx.x, head = blockIdx.y;
    int lane = threadIdx.x;
    int quad = lane >> 4, l16 = lane & 15;

    const u16* wbase = qkv + (size_t)wid * 49 * 768;

    {
        unsigned long long* z = (unsigned long long*)vT;
        for (int i = lane; i < 576; i += 64) z[i] = 0ull;
    }

    if (lane < 49) {
#pragma unroll
        for (int c = 0; c < 4; ++c) {
            u16x8 vv = *(const u16x8*)(wbase + (size_t)lane * 768 + 512 + head * 32 + c * 8);
#pragma unroll
            for (int i = 0; i < 8; ++i) vT[(c * 8 + i) * 72 + lane] = vv[i];
        }
    }

    bf16x8 aq[4], bk[4];
#pragma unroll
    for (int t = 0; t < 4; ++t) {
        int r = t * 16 + l16; r = r > 48 ? 48 : r;
        aq[t] = *(const bf16x8*)(wbase + (size_t)r * 768 + head * 32 + quad * 8);
        bk[t] = *(const bf16x8*)(wbase + (size_t)r * 768 + 256 + head * 32 + quad * 8);
    }

    f32x4 s[4][4];
#pragma unroll
    for (int tm = 0; tm < 4; ++tm)
#pragma unroll
        for (int tn = 0; tn < 4; ++tn)
            s[tm][tn] = __builtin_amdgcn_mfma_f32_16x16x32_bf16(aq[tm], bk[tn],
                        (f32x4){0.f, 0.f, 0.f, 0.f}, 0, 0, 0);

    const float scale = 0.17677669529663687f;
    const float* bt = btile + head * 4096;
#pragma unroll
    for (int tm = 0; tm < 4; ++tm)
#pragma unroll
        for (int tn = 0; tn < 4; ++tn)
#pragma unroll
            for (int r = 0; r < 4; ++r) {
                float bb = bt[(tm * 16 + quad * 4 + r) * 64 + tn * 16 + l16];
                s[tm][tn][r] = s[tm][tn][r] * scale + bb;
            }

#pragma unroll
    for (int tm = 0; tm < 4; ++tm)
#pragma unroll
        for (int r = 0; r < 4; ++r) {
            float mx = fmaxf(fmaxf(s[tm][0][r], s[tm][1][r]), fmaxf(s[tm][2][r], s[tm][3][r]));
#pragma unroll
            for (int off = 1; off < 16; off <<= 1) mx = fmaxf(mx, __shfl_xor(mx, off, 64));
            float sum = 0.f;
#pragma unroll
            for (int tn = 0; tn < 4; ++tn) {
                float e = __expf(s[tm][tn][r] - mx);
                s[tm][tn][r] = e; sum += e;
            }
#pragma unroll
            for (int off = 1; off < 16; off <<= 1) sum += __shfl_xor(sum, off, 64);
            float inv = 1.0f / sum;
#pragma unroll
            for (int tn = 0; tn < 4; ++tn) s[tm][tn][r] *= inv;
        }

    __syncthreads();
#pragma unroll
    for (int tm = 0; tm < 4; ++tm)
#pragma unroll
        for (int tn = 0; tn < 4; ++tn)
#pragma unroll
            for (int r = 0; r < 4; ++r)
                pl[(tm * 16 + quad * 4 + r) * 72 + tn * 16 + l16] = f2b(s[tm][tn][r]);
    __syncthreads();

    f32x4 oa[4][2];
#pragma unroll
    for (int tm = 0; tm < 4; ++tm)
#pragma unroll
        for (int tn = 0; tn < 2; ++tn) oa[tm][tn] = (f32x4){0.f, 0.f, 0.f, 0.f};

#pragma unroll
    for (int ks = 0; ks < 2; ++ks) {
        bf16x8 pa[4], vb[2];
#pragma unroll
        for (int tm = 0; tm < 4; ++tm)
            pa[tm] = *(const bf16x8*)(pl + (unsigned)(tm * 16 + l16) * 72 + ks * 32 + quad * 8);
#pragma unroll
        for (int tn = 0; tn < 2; ++tn)
            vb[tn] = *(const bf16x8*)(vT + (unsigned)(tn * 16 + l16) * 72 + ks * 32 + quad * 8);
#pragma unroll
        for (int tm = 0; tm < 4; ++tm)
#pragma unroll
            for (int tn = 0; tn < 2; ++tn)
                oa[tm][tn] = __builtin_amdgcn_mfma_f32_16x16x32_bf16(pa[tm], vb[tn], oa[tm][tn], 0, 0, 0);
    }

    u16* ob = o + (size_t)wid * 49 * 256 + head * 32;
#pragma unroll
    for (int tm = 0; tm < 4; ++tm)
#pragma unroll
        for (int r = 0; r < 4; ++r) {
            int m = tm * 16 + quad * 4 + r;
            if (m < 49) {
#pragma unroll
                for (int tn = 0; tn < 2; ++tn)
                    ob[(size_t)m * 256 + tn * 16 + l16] = f2b(oa[tm][tn][r]);
            }
        }
}

extern "C" void kernel_launch(void* const* d_in, const int* in_sizes, int n_in,
                              void* d_out, int out_size, void* d_ws, size_t ws_size,
                              hipStream_t stream)
{
    const float* x     = (const float*)d_in[0];
    const float* n1g   = (const float*)d_in[1];
    const float* n1b   = (const float*)d_in[2];
    const float* qkvw  = (const float*)d_in[3];
    const float* qkvb  = (const float*)d_in[4];
    const float* btab  = (const float*)d_in[5];
    const float* projw = (const float*)d_in[6];
    const float* projb = (const float*)d_in[7];
    const float* n2g   = (const float*)d_in[8];
    const float* n2b   = (const float*)d_in[9];
    const float* w1    = (const float*)d_in[10];
    const float* b1    = (const float*)d_in[11];
    const float* w2    = (const float*)d_in[12];
    const float* b2    = (const float*)d_in[13];

    char* ws  = (char*)d_ws;
    u16* x1   = (u16*)ws;                                     // bf16 residual stream
    u16* bufA = (u16*)(ws + 102760448);                       // 100352*1024*2
    u16* bufB = (u16*)(ws + 102760448 + 205520896);           // 100352*256*2
    u16* wq   = (u16*)(ws + 102760448 + 205520896 + 51380224);// bf16 weights
    u16* wp   = wq + 196608;
    u16* wf1  = wp + 65536;
    u16* wf2  = wf1 + 262144;
    float* btile = (float*)(ws + 102760448 + 154140672);      // 8*64*64 fp32

    // 0. weights fp32->bf16, bias tile
    cvt_kernel<<<192, 256, 0, stream>>>(qkvw, wq, 196608);
    cvt_kernel<<<64,  256, 0, stream>>>(projw, wp, 65536);
    cvt_kernel<<<256, 256, 0, stream>>>(w1, wf1, 262144);
    cvt_kernel<<<256, 256, 0, stream>>>(w2, wf2, 262144);
    bias_prep<<<8, 256, 0, stream>>>(btab, btile);

    // 1. LN1 + window partition (fp32 -> bf16, window-ordered)
    ln_kernel<1, 0><<<25088, 256, 0, stream>>>(x, n1g, n1b, bufB);
    // 2. QKV GEMM -> bf16 (nB=6)
    gemm_kernel<0><<<6 * 784, 256, 0, stream>>>(bufB, wq, qkvb, bufA, nullptr,
                                                nullptr, nullptr, 768, 256, 6);
    // 3. MFMA window attention -> bf16 (window-ordered)
    attn_kernel<<<dim3(2048, 8), 64, 0, stream>>>(bufA, btile, bufB);
    // 4. proj GEMM + window reverse + residual -> x1 (bf16, spatial) (nB=2)
    gemm_kernel<2><<<2 * 784, 256, 0, stream>>>(bufB, wp, projb, x1, nullptr,
                                                x, nullptr, 256, 256, 2);
    // 5. LN2 (bf16 -> bf16, spatial)
    ln_kernel<0, 1><<<25088, 256, 0, stream>>>(x1, n2g, n2b, bufB);
    // 6. FFN1 + tanh-GELU -> bf16 (nB=8)
    gemm_kernel<1><<<8 * 784, 256, 0, stream>>>(bufB, wf1, b1, bufA, nullptr,
                                                nullptr, nullptr, 1024, 256, 8);
    // 7. FFN2 + residual -> d_out (fp32) (nB=2)
    gemm_kernel<3><<<2 * 784, 256, 0, stream>>>(bufA, wf2, b2, nullptr, (float*)d_out,
                                                nullptr, x1, 256, 1024, 2);
}